// Round 7
// baseline (83.950 us; speedup 1.0000x reference)
//
#include <hip/hip_runtime.h>
#include <hip/hip_bf16.h>

#define NROWS 8192
#define NDIM  256
#define KNN   8
#define TCOL  32                          // j-cols per LDS tile (16 KiB)
#define BLK_ROWS 256                      // 4 waves x 64 rows (R=2)

typedef __attribute__((ext_vector_type(8)))  short bf16x8;
typedef __attribute__((ext_vector_type(16))) float f32x16;

// ---- workspace layout (bytes) ----
#define WS_EBF 0                          // 8192*256*2 = 4 MiB
#define WS_SQN (4*1024*1024)              // 32 KiB
#define WS_PCS (WS_SQN + 32*1024)         // 128 blocks x 256 f32 = 128 KiB
#define WS_ACC (WS_PCS + 128*1024)        // 1 KiB (gacc[0..2] + counter)
#define WS_KNN (WS_ACC + 1024)            // [jsplit][NROWS][KNN] f32

// e -> bf16, per-row squared norms, per-block column-sum partials.
// Block 0 zeroes gacc+counter (only k_final reads them; stream-ordered).
__global__ void k_prep(const float* __restrict__ e,
                       ushort* __restrict__ ebf,
                       float* __restrict__ sqn,
                       float* __restrict__ pcs,
                       float* __restrict__ gacc) {
  __shared__ float lcs[NDIM];
  const int tid  = threadIdx.x;
  const int lane = tid & 63;
  const int wv   = tid >> 6;
  if (blockIdx.x == 0 && tid < 8) ((int*)gacc)[tid] = 0;
  lcs[tid] = 0.f;
  __syncthreads();
  float4 cs = {0.f, 0.f, 0.f, 0.f};
  #pragma unroll
  for (int r = 0; r < 16; ++r) {
    const int row = blockIdx.x * 64 + wv * 16 + r;
    const float4 v = *reinterpret_cast<const float4*>(e + (size_t)row * NDIM + lane * 4);
    ushort4 o;
    __hip_bfloat16 b0 = __float2bfloat16(v.x), b1 = __float2bfloat16(v.y);
    __hip_bfloat16 b2 = __float2bfloat16(v.z), b3 = __float2bfloat16(v.w);
    o.x = *reinterpret_cast<ushort*>(&b0); o.y = *reinterpret_cast<ushort*>(&b1);
    o.z = *reinterpret_cast<ushort*>(&b2); o.w = *reinterpret_cast<ushort*>(&b3);
    *reinterpret_cast<ushort4*>(ebf + (size_t)row * NDIM + lane * 4) = o;
    float acc = v.x*v.x + v.y*v.y + v.z*v.z + v.w*v.w;
    #pragma unroll
    for (int off = 32; off > 0; off >>= 1) acc += __shfl_down(acc, off);
    if (lane == 0) sqn[row] = acc;
    cs.x += v.x; cs.y += v.y; cs.z += v.z; cs.w += v.w;
  }
  atomicAdd(&lcs[lane * 4 + 0], cs.x);
  atomicAdd(&lcs[lane * 4 + 1], cs.y);
  atomicAdd(&lcs[lane * 4 + 2], cs.z);
  atomicAdd(&lcs[lane * 4 + 3], cs.w);
  __syncthreads();
  pcs[blockIdx.x * NDIM + tid] = lcs[tid];
}

// ---- branchless compare-exchange / bitonic helpers (all-parallel) ----
__device__ __forceinline__ void CE(float& x, float& y) {
  const float lo = fminf(x, y);
  y = fmaxf(x, y);
  x = lo;
}
// full ascending sort of 8 arbitrary values (6 substeps x 4 independent CEs)
__device__ __forceinline__ void sort8(float* c) {
  CE(c[0],c[1]); CE(c[3],c[2]); CE(c[4],c[5]); CE(c[7],c[6]);
  CE(c[0],c[2]); CE(c[1],c[3]); CE(c[6],c[4]); CE(c[7],c[5]);
  CE(c[0],c[1]); CE(c[2],c[3]); CE(c[5],c[4]); CE(c[7],c[6]);
  CE(c[0],c[4]); CE(c[1],c[5]); CE(c[2],c[6]); CE(c[3],c[7]);
  CE(c[0],c[2]); CE(c[1],c[3]); CE(c[4],c[6]); CE(c[5],c[7]);
  CE(c[0],c[1]); CE(c[2],c[3]); CE(c[4],c[5]); CE(c[6],c[7]);
}
// sort a bitonic 8-sequence ascending (3 substeps x 4 independent CEs)
__device__ __forceinline__ void clean8(float* s) {
  CE(s[0],s[4]); CE(s[1],s[5]); CE(s[2],s[6]); CE(s[3],s[7]);
  CE(s[0],s[2]); CE(s[1],s[3]); CE(s[4],s[6]); CE(s[5],s[7]);
  CE(s[0],s[1]); CE(s[2],s[3]); CE(s[4],s[5]); CE(s[6],s[7]);
}
// m (sorted asc top-8) <- top-8 of m ∪ c[16]; c arbitrary, clobbered.
// Depth ~14 substeps, every substep 4-8 wide ILP (no serial med3 chain).
__device__ __forceinline__ void select16(float* __restrict__ m,
                                         float* __restrict__ c) {
  sort8(c); sort8(c + 8);
  float s[8];
  #pragma unroll
  for (int k = 0; k < 8; ++k) s[k] = fminf(c[k], c[15 - k]);  // half-cleaner
  clean8(s);
  float t[8];
  #pragma unroll
  for (int k = 0; k < 8; ++k) t[k] = fminf(s[k], m[7 - k]);   // merge with m
  clean8(t);
  #pragma unroll
  for (int k = 0; k < 8; ++k) m[k] = t[k];
}

// Fused Gram + top-8, R=2 row-blocks per wave, deferred parallel selection.
// Swapped 32x32x16 MFMA (D = jf * if): lane owns one i-row (col=lane&31).
// Selection of tile t-1's candidates runs DURING tile t's MFMA chain (the
// cA/cB arrays are independent of the current chain -> scheduler interleaves
// them into the MFMA pipe/latency shadow).
__launch_bounds__(256, 2)
__global__ void k_main(const ushort* __restrict__ eb,
                       const float* __restrict__ sqn,
                       float* __restrict__ knn_out,
                       int jrange, int jsplit) {
  __shared__ ushort lbuf[2][TCOL * NDIM];   // 2 x 16 KiB
  __shared__ float  lsqn[1024];

  const int tid  = threadIdx.x;
  const int lane = tid & 63;
  const int wv   = tid >> 6;
  const int col  = lane & 31;
  const int hi   = lane >> 5;
  const int rowA = blockIdx.x * BLK_ROWS + wv * 32 + col;
  const int rowB = rowA + 128;
  const int split = blockIdx.y;
  const int jbase = split * jrange;

  // i-fragments for both row-blocks (128 VGPRs, loop-invariant).
  bf16x8 ifA[16], ifB[16];
  #pragma unroll
  for (int kk = 0; kk < 16; ++kk) {
    ifA[kk] = *reinterpret_cast<const bf16x8*>(eb + (size_t)rowA * NDIM + kk * 16 + hi * 8);
    ifB[kk] = *reinterpret_cast<const bf16x8*>(eb + (size_t)rowB * NDIM + kk * 16 + hi * 8);
  }
  const float niA = sqn[rowA];
  const float niB = sqn[rowB];

  float mA[KNN], mB[KNN];
  #pragma unroll
  for (int i = 0; i < KNN; ++i) { mA[i] = 1e30f; mB[i] = 1e30f; }

  for (int i = tid; i < jrange; i += 256) lsqn[i] = sqn[jbase + i];

  auto stage = [&](int bufi, int jb) {
    #pragma unroll
    for (int s = 0; s < 4; ++s) {
      const int o  = s * 4096 + wv * 1024 + lane * 16;   // linear LDS byte
      const int kk = o >> 10;
      const int h  = (o >> 9) & 1;
      const int c  = ((o & 511) ^ ((kk & 7) << 4)) >> 4; // inverse swizzle on SOURCE
      const ushort* src = eb + (size_t)(jb + c) * NDIM + (kk * 2 + h) * 8;
      __builtin_amdgcn_global_load_lds(
          (const __attribute__((address_space(1))) void*)src,
          (__attribute__((address_space(3))) void*)(
              reinterpret_cast<char*>(&lbuf[bufi][0]) + s * 4096 + wv * 1024),
          16, 0, 0);
    }
  };

  // deferred candidates (selected one iteration later)
  float cA[16], cB[16];
  #pragma unroll
  for (int q = 0; q < 16; ++q) { cA[q] = 1e30f; cB[q] = 1e30f; }

  stage(0, jbase);
  asm volatile("s_waitcnt vmcnt(0)" ::: "memory");
  __syncthreads();

  const int nT = jrange / TCOL;
  int buf = 0;
  for (int it = 0; it < nT; ++it) {
    if (it + 1 < nT) stage(buf ^ 1, jbase + (it + 1) * TCOL);

    f32x16 accA, accB;
    #pragma unroll
    for (int i = 0; i < 16; ++i) { accA[i] = 0.f; accB[i] = 0.f; }
    #pragma unroll
    for (int kk = 0; kk < 16; ++kk) {
      const int b0 = (kk * 1024 + hi * 512 + col * 16) ^ ((kk & 7) << 4);
      const bf16x8 jf = *reinterpret_cast<const bf16x8*>(
          reinterpret_cast<const char*>(&lbuf[buf][0]) + b0);
      accA = __builtin_amdgcn_mfma_f32_32x32x16_bf16(jf, ifA[kk], accA, 0, 0, 0);
      accB = __builtin_amdgcn_mfma_f32_32x32x16_bf16(jf, ifB[kk], accB, 0, 0, 0);
    }

    // select PREVIOUS tile's candidates (independent of the chain above)
    select16(mA, cA);
    select16(mB, cB);

    // new candidates: w = nj - 2*dot (monotone in sq = ni + w)
    #pragma unroll
    for (int g = 0; g < 4; ++g) {
      const float4 nj = *reinterpret_cast<const float4*>(&lsqn[it * TCOL + g * 8 + hi * 4]);
      const float njv[4] = {nj.x, nj.y, nj.z, nj.w};
      #pragma unroll
      for (int q = 0; q < 4; ++q) {
        cA[g*4+q] = fmaf(-2.0f, accA[g*4+q], njv[q]);
        cB[g*4+q] = fmaf(-2.0f, accB[g*4+q], njv[q]);
      }
    }

    asm volatile("s_waitcnt vmcnt(0)" ::: "memory");
    __syncthreads();
    buf ^= 1;
  }
  // final deferred selection
  select16(mA, cA);
  select16(mB, cB);

  // merge k-half lists (lane <-> lane+32): mins of two sorted-8 lists are
  // elementwise min(a_k, b_{7-k}); hi==0 lanes write (bitonic order is fine
  // for k_final, but keep ascending via clean for exactness of layout).
  float g[KNN];
  #pragma unroll
  for (int k = 0; k < KNN; ++k)
    g[k] = fminf(mA[k], __shfl_xor(mA[KNN - 1 - k], 32));
  if (hi == 0) {
    float* dst = knn_out + ((size_t)split * NROWS + rowA) * KNN;
    #pragma unroll
    for (int k = 0; k < KNN; ++k) dst[k] = fmaxf(niA + g[k], 0.0f);
  }
  #pragma unroll
  for (int k = 0; k < KNN; ++k)
    g[k] = fminf(mB[k], __shfl_xor(mB[KNN - 1 - k], 32));
  if (hi == 0) {
    float* dst = knn_out + ((size_t)split * NROWS + rowB) * KNN;
    #pragma unroll
    for (int k = 0; k < KNN; ++k) dst[k] = fmaxf(niB + g[k], 0.0f);
  }
}

// Merge jsplit 8-sets per row; reduce sum8/S2; block 0 reduces colsum
// partials -> Q; last finishing block computes the output scalar.
__global__ void k_final(const float* __restrict__ knn,
                        const float* __restrict__ sqn,
                        const float* __restrict__ pcs,
                        float* __restrict__ gacc,
                        float* __restrict__ out, int jsplit) {
  const int tid = threadIdx.x;
  const int row = blockIdx.x * blockDim.x + tid;
  float m[KNN];
  #pragma unroll
  for (int i = 0; i < KNN; ++i) m[i] = 1e30f;
  for (int s = 0; s < jsplit; ++s) {
    const float* p = knn + ((size_t)s * NROWS + row) * KNN;
    #pragma unroll
    for (int i = 0; i < KNN; ++i) {
      const float c = p[i];
      m[7] = __builtin_amdgcn_fmed3f(m[6], m[7], c);
      m[6] = __builtin_amdgcn_fmed3f(m[5], m[6], c);
      m[5] = __builtin_amdgcn_fmed3f(m[4], m[5], c);
      m[4] = __builtin_amdgcn_fmed3f(m[3], m[4], c);
      m[3] = __builtin_amdgcn_fmed3f(m[2], m[3], c);
      m[2] = __builtin_amdgcn_fmed3f(m[1], m[2], c);
      m[1] = __builtin_amdgcn_fmed3f(m[0], m[1], c);
      m[0] = fminf(m[0], c);
    }
  }
  float rs = 0.f;
  #pragma unroll
  for (int i = 0; i < KNN; ++i) rs += m[i];
  float s2 = sqn[row];

  __shared__ float red[2][4];
  #pragma unroll
  for (int off = 32; off > 0; off >>= 1) {
    rs += __shfl_down(rs, off);
    s2 += __shfl_down(s2, off);
  }
  if ((tid & 63) == 0) { red[0][tid >> 6] = rs; red[1][tid >> 6] = s2; }
  __syncthreads();
  if (tid == 0) {
    atomicAdd(&gacc[0], red[0][0] + red[0][1] + red[0][2] + red[0][3]);
    atomicAdd(&gacc[1], red[1][0] + red[1][1] + red[1][2] + red[1][3]);
  }
  if (blockIdx.x == 0) {
    float s = 0.f;
    for (int b = 0; b < 128; ++b) s += pcs[b * NDIM + tid];
    float q = s * s;
    #pragma unroll
    for (int off = 32; off > 0; off >>= 1) q += __shfl_down(q, off);
    __syncthreads();
    if ((tid & 63) == 0) red[0][tid >> 6] = q;
    __syncthreads();
    if (tid == 0) atomicAdd(&gacc[2], red[0][0] + red[0][1] + red[0][2] + red[0][3]);
  }
  // completion: last block computes the output scalar.
  if (tid == 0) {
    __threadfence();
    int* cnt = (int*)(gacc + 3);
    const int prev = atomicAdd(cnt, 1);
    if (prev == (int)gridDim.x - 1) {
      const float sum8 = atomicAdd(&gacc[0], 0.0f);
      const float S2   = atomicAdd(&gacc[1], 0.0f);
      const float Q    = atomicAdd(&gacc[2], 0.0f);
      const float ref_var = (S2 - Q / (float)NROWS) / ((float)NDIM * (float)(NROWS - 1));
      out[0] = (sum8 / (float)(NROWS * KNN)) / ref_var;
    }
  }
}

extern "C" void kernel_launch(void* const* d_in, const int* in_sizes, int n_in,
                              void* d_out, int out_size, void* d_ws, size_t ws_size,
                              hipStream_t stream) {
  const float* e = (const float*)d_in[0];
  char* ws = (char*)d_ws;
  ushort* ebf = (ushort*)(ws + WS_EBF);
  float* sqn  = (float*)(ws + WS_SQN);
  float* pcs  = (float*)(ws + WS_PCS);
  float* gacc = (float*)(ws + WS_ACC);
  float* knn  = (float*)(ws + WS_KNN);
  float* out  = (float*)d_out;

  const size_t need16 = (size_t)WS_KNN + (size_t)NROWS * 16 * KNN * 4;
  const int jsplit = (ws_size >= need16) ? 16 : 8;
  const int jrange = NROWS / jsplit;

  hipLaunchKernelGGL(k_prep,  dim3(128), dim3(256), 0, stream, e, ebf, sqn, pcs, gacc);
  hipLaunchKernelGGL(k_main,  dim3(NROWS / BLK_ROWS, jsplit), dim3(256), 0, stream,
                     ebf, sqn, knn, jrange, jsplit);
  hipLaunchKernelGGL(k_final, dim3(NROWS / 256), dim3(256), 0, stream,
                     knn, sqn, pcs, gacc, out, jsplit);
}

// Round 8
// 83.473 us; speedup vs baseline: 1.0057x; 1.0057x over previous
//
#include <hip/hip_runtime.h>
#include <hip/hip_bf16.h>

#define NROWS 8192
#define NDIM  256
#define KNN   8
#define TCOL  32                          // j-cols per tile-iteration
#define BLK_ROWS 256                      // 4 waves x 64 rows (R=2)
#define JSPLIT 16
#define JRANGE (NROWS / JSPLIT)

typedef __attribute__((ext_vector_type(8)))  short bf16x8;
typedef __attribute__((ext_vector_type(16))) float f32x16;

// ---- workspace layout (bytes) ----
// ebT: chunk-major bf16: uint4 ebT[32][8192] — chunk c holds dims 8c..8c+7
// of every row as one 16B quad. A 32-row j-fragment load = 512B contiguous.
#define WS_EBT 0                          // 4 MiB
#define WS_SQN (4*1024*1024)              // 32 KiB
#define WS_PCS (WS_SQN + 32*1024)         // 128 x 256 f32 = 128 KiB
#define WS_ACC (WS_PCS + 128*1024)        // gacc[0..2] + counter
#define WS_KNN (WS_ACC + 1024)            // [JSPLIT][NROWS][KNN] f32 = 4 MiB

// e -> bf16 chunk-major, per-row squared norms, per-block colsum partials.
// Block 0 zeroes gacc+counter (only k_final reads them; stream-ordered).
__global__ void k_prep(const float* __restrict__ e,
                       ushort* __restrict__ ebt,
                       float* __restrict__ sqn,
                       float* __restrict__ pcs,
                       float* __restrict__ gacc) {
  __shared__ float lcs[NDIM];
  const int tid  = threadIdx.x;
  const int lane = tid & 63;
  const int wv   = tid >> 6;
  if (blockIdx.x == 0 && tid < 8) ((int*)gacc)[tid] = 0;
  lcs[tid] = 0.f;
  __syncthreads();
  const int chunk = lane >> 1;            // this lane's 4 dims live in chunk
  const int half  = lane & 1;
  float4 cs = {0.f, 0.f, 0.f, 0.f};
  #pragma unroll
  for (int r = 0; r < 16; ++r) {
    const int row = blockIdx.x * 64 + wv * 16 + r;
    const float4 v = *reinterpret_cast<const float4*>(e + (size_t)row * NDIM + lane * 4);
    ushort4 o;
    __hip_bfloat16 b0 = __float2bfloat16(v.x), b1 = __float2bfloat16(v.y);
    __hip_bfloat16 b2 = __float2bfloat16(v.z), b3 = __float2bfloat16(v.w);
    o.x = *reinterpret_cast<ushort*>(&b0); o.y = *reinterpret_cast<ushort*>(&b1);
    o.z = *reinterpret_cast<ushort*>(&b2); o.w = *reinterpret_cast<ushort*>(&b3);
    *reinterpret_cast<ushort4*>(ebt + ((size_t)(chunk * NROWS + row) * 8 + half * 4)) = o;
    float acc = v.x*v.x + v.y*v.y + v.z*v.z + v.w*v.w;
    #pragma unroll
    for (int off = 32; off > 0; off >>= 1) acc += __shfl_down(acc, off);
    if (lane == 0) sqn[row] = acc;
    cs.x += v.x; cs.y += v.y; cs.z += v.z; cs.w += v.w;
  }
  atomicAdd(&lcs[lane * 4 + 0], cs.x);
  atomicAdd(&lcs[lane * 4 + 1], cs.y);
  atomicAdd(&lcs[lane * 4 + 2], cs.z);
  atomicAdd(&lcs[lane * 4 + 3], cs.w);
  __syncthreads();
  pcs[blockIdx.x * NDIM + tid] = lcs[tid];
}

// ---- selection helpers ----
__device__ __forceinline__ void CE(float& x, float& y) {
  const float lo = fminf(x, y);
  y = fmaxf(x, y);
  x = lo;
}
// sort a bitonic 8-sequence ascending (3 substeps x 4 independent CEs)
__device__ __forceinline__ void clean8(float* s) {
  CE(s[0],s[4]); CE(s[1],s[5]); CE(s[2],s[6]); CE(s[3],s[7]);
  CE(s[0],s[2]); CE(s[1],s[3]); CE(s[4],s[6]); CE(s[5],s[7]);
  CE(s[0],s[1]); CE(s[2],s[3]); CE(s[4],s[5]); CE(s[6],s[7]);
}
// sorted-ascending top-8 insert (med3 network)
__device__ __forceinline__ void ins8(float* m, const float c) {
  m[7] = __builtin_amdgcn_fmed3f(m[6], m[7], c);
  m[6] = __builtin_amdgcn_fmed3f(m[5], m[6], c);
  m[5] = __builtin_amdgcn_fmed3f(m[4], m[5], c);
  m[4] = __builtin_amdgcn_fmed3f(m[3], m[4], c);
  m[3] = __builtin_amdgcn_fmed3f(m[2], m[3], c);
  m[2] = __builtin_amdgcn_fmed3f(m[1], m[2], c);
  m[1] = __builtin_amdgcn_fmed3f(m[0], m[1], c);
  m[0] = fminf(m[0], c);
}

// Fused Gram + top-8. NO LDS, NO BARRIERS: chunk-major ebT makes every
// j-fragment wave-load two contiguous 512B segments served by L1/L2
// (4 MiB table is L2-resident per XCD; a block's 4 waves share the 16 KiB
// tile footprint through L1). Waves free-run — no 2-phase lockstep.
// Swapped 32x32x16 MFMA (D = jf * if): lane owns i-row col=lane&31; R=2.
__launch_bounds__(256, 2)
__global__ void k_main(const uint4* __restrict__ ebT,
                       const float* __restrict__ sqn,
                       float* __restrict__ knn_out) {
  const int tid  = threadIdx.x;
  const int lane = tid & 63;
  const int wv   = tid >> 6;
  const int col  = lane & 31;
  const int hi   = lane >> 5;
  const int rowA = blockIdx.x * BLK_ROWS + wv * 32 + col;
  const int rowB = rowA + 128;
  const int split = blockIdx.y;
  const int jbase = split * JRANGE;

  // i-fragments for both row-blocks (coalesced 512B wave segments).
  bf16x8 ifA[16], ifB[16];
  #pragma unroll
  for (int kk = 0; kk < 16; ++kk) {
    const uint4 a = ebT[(size_t)(2 * kk + hi) * NROWS + rowA];
    const uint4 b = ebT[(size_t)(2 * kk + hi) * NROWS + rowB];
    ifA[kk] = *reinterpret_cast<const bf16x8*>(&a);
    ifB[kk] = *reinterpret_cast<const bf16x8*>(&b);
  }
  const float niA = sqn[rowA];
  const float niB = sqn[rowB];

  float mA[KNN], mB[KNN];
  #pragma unroll
  for (int i = 0; i < KNN; ++i) { mA[i] = 1e30f; mB[i] = 1e30f; }

  for (int it = 0; it < JRANGE / TCOL; ++it) {
    const int jb = jbase + it * TCOL;

    // nj for this tile (L1-resident broadcast loads, shared A/B)
    float njv[16];
    #pragma unroll
    for (int g = 0; g < 4; ++g) {
      const float4 t = *reinterpret_cast<const float4*>(sqn + jb + g * 8 + hi * 4);
      njv[g*4+0] = t.x; njv[g*4+1] = t.y; njv[g*4+2] = t.z; njv[g*4+3] = t.w;
    }

    f32x16 accA, accB;
    #pragma unroll
    for (int i = 0; i < 16; ++i) { accA[i] = 0.f; accB[i] = 0.f; }
    #pragma unroll
    for (int kk = 0; kk < 16; ++kk) {
      const uint4 j4 = ebT[(size_t)(2 * kk + hi) * NROWS + jb + col];
      const bf16x8 jf = *reinterpret_cast<const bf16x8*>(&j4);
      accA = __builtin_amdgcn_mfma_f32_32x32x16_bf16(jf, ifA[kk], accA, 0, 0, 0);
      accB = __builtin_amdgcn_mfma_f32_32x32x16_bf16(jf, ifB[kk], accB, 0, 0, 0);
    }

    // selection on w = nj - 2*dot (monotone in sq = ni + w)
    #pragma unroll
    for (int q = 0; q < 16; ++q) ins8(mA, fmaf(-2.0f, accA[q], njv[q]));
    #pragma unroll
    for (int q = 0; q < 16; ++q) ins8(mB, fmaf(-2.0f, accB[q], njv[q]));
  }

  // merge k-half lists (lane <-> lane+32): min(a_k, b_{7-k}) is the top-8
  // (bitonic); clean8 -> sorted ascending so k_final can min-merge.
  float g[KNN];
  #pragma unroll
  for (int k = 0; k < KNN; ++k)
    g[k] = fminf(mA[k], __shfl_xor(mA[KNN - 1 - k], 32));
  clean8(g);
  if (hi == 0) {
    float* dst = knn_out + ((size_t)split * NROWS + rowA) * KNN;
    #pragma unroll
    for (int k = 0; k < KNN; ++k) dst[k] = fmaxf(niA + g[k], 0.0f);
  }
  #pragma unroll
  for (int k = 0; k < KNN; ++k)
    g[k] = fminf(mB[k], __shfl_xor(mB[KNN - 1 - k], 32));
  clean8(g);
  if (hi == 0) {
    float* dst = knn_out + ((size_t)split * NROWS + rowB) * KNN;
    #pragma unroll
    for (int k = 0; k < KNN; ++k) dst[k] = fmaxf(niB + g[k], 0.0f);
  }
}

// Merge JSPLIT sorted 8-lists per row (min-merge + clean8, 32 ops/split),
// reduce sum8/S2; block 0 reduces colsum partials -> Q; last block -> out.
__global__ void k_final(const float* __restrict__ knn,
                        const float* __restrict__ sqn,
                        const float* __restrict__ pcs,
                        float* __restrict__ gacc,
                        float* __restrict__ out) {
  const int tid = threadIdx.x;
  const int row = blockIdx.x * blockDim.x + tid;
  float m[KNN];
  const float* p0 = knn + (size_t)row * KNN;
  #pragma unroll
  for (int i = 0; i < KNN; ++i) m[i] = p0[i];
  for (int s = 1; s < JSPLIT; ++s) {
    const float* p = knn + ((size_t)s * NROWS + row) * KNN;
    float b[KNN];
    #pragma unroll
    for (int i = 0; i < KNN; ++i) b[i] = p[i];
    #pragma unroll
    for (int k = 0; k < KNN; ++k) m[k] = fminf(m[k], b[KNN - 1 - k]);
    clean8(m);
  }
  float rs = 0.f;
  #pragma unroll
  for (int i = 0; i < KNN; ++i) rs += m[i];
  float s2 = sqn[row];

  __shared__ float red[2][4];
  #pragma unroll
  for (int off = 32; off > 0; off >>= 1) {
    rs += __shfl_down(rs, off);
    s2 += __shfl_down(s2, off);
  }
  if ((tid & 63) == 0) { red[0][tid >> 6] = rs; red[1][tid >> 6] = s2; }
  __syncthreads();
  if (tid == 0) {
    atomicAdd(&gacc[0], red[0][0] + red[0][1] + red[0][2] + red[0][3]);
    atomicAdd(&gacc[1], red[1][0] + red[1][1] + red[1][2] + red[1][3]);
  }
  if (blockIdx.x == 0) {
    float s = 0.f;
    for (int b = 0; b < 128; ++b) s += pcs[b * NDIM + tid];
    float q = s * s;
    #pragma unroll
    for (int off = 32; off > 0; off >>= 1) q += __shfl_down(q, off);
    __syncthreads();
    if ((tid & 63) == 0) red[0][tid >> 6] = q;
    __syncthreads();
    if (tid == 0) atomicAdd(&gacc[2], red[0][0] + red[0][1] + red[0][2] + red[0][3]);
  }
  // completion: last block computes the output scalar.
  if (tid == 0) {
    __threadfence();
    int* cnt = (int*)(gacc + 3);
    const int prev = atomicAdd(cnt, 1);
    if (prev == (int)gridDim.x - 1) {
      const float sum8 = atomicAdd(&gacc[0], 0.0f);
      const float S2   = atomicAdd(&gacc[1], 0.0f);
      const float Q    = atomicAdd(&gacc[2], 0.0f);
      const float ref_var = (S2 - Q / (float)NROWS) / ((float)NDIM * (float)(NROWS - 1));
      out[0] = (sum8 / (float)(NROWS * KNN)) / ref_var;
    }
  }
}

extern "C" void kernel_launch(void* const* d_in, const int* in_sizes, int n_in,
                              void* d_out, int out_size, void* d_ws, size_t ws_size,
                              hipStream_t stream) {
  const float* e = (const float*)d_in[0];
  char* ws = (char*)d_ws;
  ushort* ebt = (ushort*)(ws + WS_EBT);
  float* sqn  = (float*)(ws + WS_SQN);
  float* pcs  = (float*)(ws + WS_PCS);
  float* gacc = (float*)(ws + WS_ACC);
  float* knn  = (float*)(ws + WS_KNN);
  float* out  = (float*)d_out;

  hipLaunchKernelGGL(k_prep,  dim3(128), dim3(256), 0, stream, e, ebt, sqn, pcs, gacc);
  hipLaunchKernelGGL(k_main,  dim3(NROWS / BLK_ROWS, JSPLIT), dim3(256), 0, stream,
                     (const uint4*)ebt, sqn, knn);
  hipLaunchKernelGGL(k_final, dim3(NROWS / 256), dim3(256), 0, stream,
                     knn, sqn, pcs, gacc, out);
}